// Round 1
// 329.487 us; speedup vs baseline: 1.7960x; 1.7960x over previous
//
#include <hip/hip_runtime.h>

typedef unsigned short u16;
typedef __attribute__((ext_vector_type(8))) short short8;
typedef __attribute__((ext_vector_type(4))) float f32x4;

__device__ __forceinline__ u16 f2bf(float f) {
    union { float f; unsigned u; } v; v.f = f;
    unsigned r = v.u + 0x7fffu + ((v.u >> 16) & 1u);
    return (u16)(r >> 16);
}
__device__ __forceinline__ float bf2f(u16 h) {
    union { unsigned u; float f; } v; v.u = ((unsigned)h) << 16;
    return v.f;
}

// async global->LDS, 16B per lane. LDS dest is wave-uniform base + lane*16,
// our addressing is linear in tid so this holds.
__device__ __forceinline__ void gld16(const void* g, void* l) {
    __builtin_amdgcn_global_load_lds(
        (const __attribute__((address_space(1))) unsigned int*)(unsigned long long)g,
        (__attribute__((address_space(3))) unsigned int*)(unsigned int)(unsigned long long)l,
        16, 0, 0);
}

#define MFMA16(a, b, c) __builtin_amdgcn_mfma_f32_16x16x32_bf16((a), (b), (c), 0, 0, 0)

// ---------------------------------------------------------------------------
// prep: fp32 weights -> bf16 (layout [c_out][c_in], K-major for A*B^T GEMM)
// also packs the three projection biases contiguously for the fused QKV GEMM.
// ---------------------------------------------------------------------------
__global__ void prep_k(const float* __restrict__ Wq, const float* __restrict__ Wk,
                       const float* __restrict__ Wv, const float* __restrict__ Wp,
                       u16* __restrict__ wq, u16* __restrict__ wk,
                       u16* __restrict__ wv, u16* __restrict__ wp,
                       const float* __restrict__ bq, const float* __restrict__ bk,
                       const float* __restrict__ bv, float* __restrict__ bpack) {
    int i = blockIdx.x * 256 + threadIdx.x;   // 65536 threads, 4 elems each
    {
        float4 v = ((const float4*)Wq)[i];
        ushort4 o; o.x = f2bf(v.x); o.y = f2bf(v.y); o.z = f2bf(v.z); o.w = f2bf(v.w);
        ((ushort4*)wq)[i] = o;
    }
    {
        float4 v = ((const float4*)Wk)[i];
        ushort4 o; o.x = f2bf(v.x); o.y = f2bf(v.y); o.z = f2bf(v.z); o.w = f2bf(v.w);
        ((ushort4*)wk)[i] = o;
    }
    {
        float4 v = ((const float4*)Wv)[i];
        ushort4 o; o.x = f2bf(v.x); o.y = f2bf(v.y); o.z = f2bf(v.z); o.w = f2bf(v.w);
        ((ushort4*)wv)[i] = o;
    }
    {
        float4 v = ((const float4*)Wp)[i];
        ushort4 o; o.x = f2bf(v.x); o.y = f2bf(v.y); o.z = f2bf(v.z); o.w = f2bf(v.w);
        ((ushort4*)wp)[i] = o;
    }
    if (i < 512) {
        bpack[i]        = bq[i];
        bpack[512 + i]  = bk[i];
        bpack[1024 + i] = bv[i];
    }
}

// ---------------------------------------------------------------------------
// GroupNorm stats: one block per (b, group); slab is contiguous 65536 floats.
// ---------------------------------------------------------------------------
__global__ void gn_stats_k(const float* __restrict__ x, float2* __restrict__ ms) {
    const int bg = blockIdx.x;
    const float4* p = (const float4*)(x + (size_t)bg * 65536);
    float s = 0.f, q = 0.f;
    for (int i = threadIdx.x; i < 16384; i += 256) {
        float4 v = p[i];
        s += v.x + v.y + v.z + v.w;
        q += v.x * v.x + v.y * v.y + v.z * v.z + v.w * v.w;
    }
#pragma unroll
    for (int o = 32; o > 0; o >>= 1) {
        s += __shfl_down(s, o);
        q += __shfl_down(q, o);
    }
    __shared__ float sw[4], qw[4];
    if ((threadIdx.x & 63) == 0) { sw[threadIdx.x >> 6] = s; qw[threadIdx.x >> 6] = q; }
    __syncthreads();
    if (threadIdx.x == 0) {
        s = sw[0] + sw[1] + sw[2] + sw[3];
        q = qw[0] + qw[1] + qw[2] + qw[3];
        float mu = s * (1.f / 65536.f);
        float var = q * (1.f / 65536.f) - mu * mu;
        ms[bg] = make_float2(mu, rsqrtf(var + 1e-6f));
    }
}

// ---------------------------------------------------------------------------
// GN apply + transpose: x[b][c][n] (fp32) -> xt[b*4096+n][c] (bf16)
// 64x64 tile through LDS, both global sides coalesced.
// ---------------------------------------------------------------------------
__global__ void gn_apply_k(const float* __restrict__ x, const float2* __restrict__ ms,
                           const float* __restrict__ gw, const float* __restrict__ gb,
                           u16* __restrict__ xt) {
    __shared__ float tile[64][65];
    const int c0 = blockIdx.x * 64, n0 = blockIdx.y * 64, b = blockIdx.z;
    const int t = threadIdx.x;
    const float* xb = x + ((size_t)b * 512 + c0) * 4096 + n0;
    {
        const int cc = t >> 2;
        const int no = (t & 3) * 16;
#pragma unroll
        for (int i = 0; i < 4; ++i) {
            float4 v = *(const float4*)(xb + (size_t)cc * 4096 + no + i * 4);
            tile[cc][no + i * 4 + 0] = v.x;
            tile[cc][no + i * 4 + 1] = v.y;
            tile[cc][no + i * 4 + 2] = v.z;
            tile[cc][no + i * 4 + 3] = v.w;
        }
    }
    __syncthreads();
    const int c = t & 63;
    const int gc = c0 + c;
    const float2 m = ms[b * 32 + (gc >> 4)];
    const float w = gw[gc] * m.y;
    const float bb = gb[gc] - m.x * w;
#pragma unroll
    for (int j = 0; j < 16; ++j) {
        int n = j * 4 + (t >> 6);
        xt[((size_t)b * 4096 + n0 + n) * 512 + gc] = f2bf(tile[c][n] * w + bb);
    }
}

// ---------------------------------------------------------------------------
// Unified bf16 GEMM: C[r][c] = sum_k A[r][k] * B[c][k]   (A: MxK, B: NxK)
// 128x128 tile, BK=64, 4 waves (2x2), 4x4 16x16 frags per wave (m97 structure).
// blockIdx.z selects a batch/slice: A += z*azs, B += z*bzs, outv += z*ozs.
// MODE 1: bf16 store of exp(val*scale)   (P = exp(QK^T * s))
// MODE 2: bf16 store of val / rowsum(A)  (ctx; rowsum via ones-MFMA)
// MODE 3: fp32 store + bias + residual   (final out)
// MODE 5: fused QKV projection: z=0 -> Q, z=1 -> K (bf16+bias),
//         z=2 -> V (bf16+bias, transposed store to Vt[b][c][n]).
//         bias = bpack + z*512; weights contiguous with stride bzs.
// ---------------------------------------------------------------------------
template <int MODE>
__global__ __launch_bounds__(256) void gemm_k(
    const u16* __restrict__ A, const u16* __restrict__ B, int K, int ldo,
    u16* __restrict__ outv, float* __restrict__ outf,
    const float* __restrict__ bias, const float* __restrict__ xres, float scale,
    size_t azs, size_t bzs, size_t ozs) {
    __shared__ u16 As[128 * 64];
    __shared__ u16 Bs[128 * 64];
    const int bz = blockIdx.z;
    A += (size_t)bz * azs;
    B += (size_t)bz * bzs;
    if constexpr (MODE == 1 || MODE == 2 || MODE == 5) outv += (size_t)bz * ozs;
    if constexpr (MODE == 5) bias += (size_t)bz * 512;

    const int tid = threadIdx.x;
    const int lane = tid & 63;
    const int wid = tid >> 6;
    const int wr = (wid >> 1) * 64, wc = (wid & 1) * 64;
    const int lr = lane & 15, lq = lane >> 4;
    const size_t arow0 = (size_t)blockIdx.x * 128;
    const size_t brow0 = (size_t)blockIdx.y * 128;

    f32x4 acc[4][4];
#pragma unroll
    for (int m = 0; m < 4; ++m)
#pragma unroll
        for (int n = 0; n < 4; ++n) acc[m][n] = (f32x4){0.f, 0.f, 0.f, 0.f};

    f32x4 accl[4];
#pragma unroll
    for (int m = 0; m < 4; ++m) accl[m] = (f32x4){0.f, 0.f, 0.f, 0.f};

    short8 ones;
#pragma unroll
    for (int e = 0; e < 8; ++e) ones[e] = (short)0x3F80;  // bf16 1.0

    const int srow = tid >> 3;          // staging row within 32-row slab
    const int sko = (tid & 7) * 8;      // staging k offset (elements)
    const u16* Ag = A + arow0 * (size_t)K + sko;
    const u16* Bg = B + brow0 * (size_t)K + sko;

    for (int k0 = 0; k0 < K; k0 += 64) {
#pragma unroll
        for (int i = 0; i < 4; ++i) {
            int row = i * 32 + srow;
            gld16(Ag + (size_t)row * K + k0, &As[row * 64 + sko]);
            gld16(Bg + (size_t)row * K + k0, &Bs[row * 64 + sko]);
        }
        __syncthreads();
#pragma unroll
        for (int ks = 0; ks < 2; ++ks) {
            short8 af[4], bfr[4];
#pragma unroll
            for (int m = 0; m < 4; ++m)
                af[m] = *(const short8*)&As[(wr + m * 16 + lr) * 64 + ks * 32 + lq * 8];
#pragma unroll
            for (int n = 0; n < 4; ++n)
                bfr[n] = *(const short8*)&Bs[(wc + n * 16 + lr) * 64 + ks * 32 + lq * 8];
#pragma unroll
            for (int m = 0; m < 4; ++m)
#pragma unroll
                for (int n = 0; n < 4; ++n) acc[m][n] = MFMA16(af[m], bfr[n], acc[m][n]);
            if constexpr (MODE == 2) {
#pragma unroll
                for (int m = 0; m < 4; ++m) accl[m] = MFMA16(af[m], ones, accl[m]);
            }
        }
        __syncthreads();
    }

#pragma unroll
    for (int m = 0; m < 4; ++m) {
        const int rbase = (int)arow0 + wr + m * 16 + lq * 4;
#pragma unroll
        for (int n = 0; n < 4; ++n) {
            const int c = (int)brow0 + wc + n * 16 + lr;
            f32x4 v = acc[m][n];
#pragma unroll
            for (int j = 0; j < 4; ++j) {
                const int r = rbase + j;
                float val = v[j];
                if constexpr (MODE == 1) {
                    outv[(size_t)r * ldo + c] = f2bf(__expf(val * scale));
                } else if constexpr (MODE == 2) {
                    outv[(size_t)r * ldo + c] = f2bf(val / accl[m][j]);
                } else if constexpr (MODE == 3) {
                    outf[(size_t)r * ldo + c] = val + bias[c] + xres[(size_t)r * ldo + c];
                } else if constexpr (MODE == 5) {
                    float o = val + bias[c];
                    if (bz < 2) {
                        outv[(size_t)r * ldo + c] = f2bf(o);
                    } else {  // V: transposed store Vt[b][c][n]
                        outv[(size_t)(r >> 12) * 2097152 + (size_t)c * 4096 + (r & 4095)] =
                            f2bf(o);
                    }
                }
            }
        }
    }
}

// ---------------------------------------------------------------------------
// launch
// ---------------------------------------------------------------------------
extern "C" void kernel_launch(void* const* d_in, const int* in_sizes, int n_in,
                              void* d_out, int out_size, void* d_ws, size_t ws_size,
                              hipStream_t stream) {
    const float* x  = (const float*)d_in[0];
    const float* Wq = (const float*)d_in[1];
    const float* bq = (const float*)d_in[2];
    const float* Wk = (const float*)d_in[3];
    const float* bk = (const float*)d_in[4];
    const float* Wv = (const float*)d_in[5];
    const float* bv = (const float*)d_in[6];
    const float* Wp = (const float*)d_in[7];
    const float* bp = (const float*)d_in[8];
    const float* gw = (const float*)d_in[9];
    const float* gb = (const float*)d_in[10];

    char* ws = (char*)d_ws;
    const size_t MB = (size_t)1 << 20;
    // Batched path needs: 64MB (xt,Qb,Kb,Vt) + 128MB (P all batches) + ~2MB weights.
    const bool batched = ws_size >= 195 * MB;

    u16* xt = (u16*)(ws);                    // 16 MB  [16384][512]   (also ctx)
    u16* Qb = (u16*)(ws + 16 * MB);          // 16 MB
    u16* Kb = (u16*)(ws + 32 * MB);          // 16 MB  (contiguous after Qb)
    u16* Vt = (u16*)(ws + 48 * MB);          // 16 MB  [4][512][4096] (contiguous after Kb)
    u16* P  = (u16*)(ws + 64 * MB);          // 128 MB batched ([4][4096][4096]) / 32 MB fallback
    char* wbase = ws + (batched ? 192 * MB : 96 * MB);
    u16* wq = (u16*)(wbase);
    u16* wk = (u16*)(wbase + 512 * 1024);
    u16* wv = (u16*)(wbase + 1 * MB);
    u16* wp = (u16*)(wbase + 1 * MB + 512 * 1024);
    float* bpack = (float*)(wbase + 2 * MB);         // 3*512 floats
    float2* ms = (float2*)(wbase + 2 * MB + 8192);   // 128 * 8B
    u16* ctx = xt;

    prep_k<<<dim3(256), dim3(256), 0, stream>>>(Wq, Wk, Wv, Wp, wq, wk, wv, wp,
                                                bq, bk, bv, bpack);
    gn_stats_k<<<dim3(128), dim3(256), 0, stream>>>(x, ms);
    gn_apply_k<<<dim3(8, 64, 4), dim3(256), 0, stream>>>(x, ms, gw, gb, xt);

    const float iscale = 0.044194173824159216f;  // 512^-0.5

    // Fused Q/K/V projection: z=0 Q, z=1 K, z=2 V(transposed).
    // weights stride 262144 elems (512KB); Qb/Kb/Vt stride 8388608 elems (16MB).
    gemm_k<5><<<dim3(128, 4, 3), dim3(256), 0, stream>>>(
        xt, wq, 512, 512, Qb, nullptr, bpack, nullptr, 0.f,
        (size_t)0, (size_t)262144, (size_t)8388608);

    if (batched) {
        // All 4 batches in one dispatch each: P then ctx.
        gemm_k<1><<<dim3(32, 32, 4), dim3(256), 0, stream>>>(
            Qb, Kb, 512, 4096, P, nullptr, nullptr, nullptr, iscale,
            (size_t)2097152, (size_t)2097152, (size_t)16777216);
        gemm_k<2><<<dim3(32, 4, 4), dim3(256), 0, stream>>>(
            P, Vt, 4096, 512, ctx, nullptr, nullptr, nullptr, 0.f,
            (size_t)16777216, (size_t)2097152, (size_t)2097152);
    } else {
        for (int b = 0; b < 4; ++b) {
            const size_t o = (size_t)b * 4096 * 512;
            gemm_k<1><<<dim3(32, 32), dim3(256), 0, stream>>>(
                Qb + o, Kb + o, 512, 4096, P, nullptr, nullptr, nullptr, iscale,
                (size_t)0, (size_t)0, (size_t)0);
            gemm_k<2><<<dim3(32, 4), dim3(256), 0, stream>>>(
                P, Vt + o, 4096, 512, ctx + o, nullptr, nullptr, nullptr, 0.f,
                (size_t)0, (size_t)0, (size_t)0);
        }
    }
    gemm_k<3><<<dim3(128, 4), dim3(256), 0, stream>>>(
        ctx, wp, 512, 512, nullptr, (float*)d_out, bp, x, 0.f,
        (size_t)0, (size_t)0, (size_t)0);
}